// Round 10
// baseline (314.772 us; speedup 1.0000x reference)
//
#include <hip/hip_runtime.h>
#include <stdint.h>
#include <stddef.h>

typedef __attribute__((ext_vector_type(8))) short short8;
typedef __attribute__((ext_vector_type(4))) float floatx4;
typedef __attribute__((ext_vector_type(2))) float floatx2;
typedef __attribute__((ext_vector_type(2))) unsigned int uintx2;
typedef __attribute__((ext_vector_type(4))) unsigned int uintx4;
typedef __attribute__((ext_vector_type(4))) int intx4;

#define HW_IN   4096       // 64*64
#define HW_GO   3844       // 62*62
#define OUT_ELEMS 294912   // 256*128*9
#define NCHUNK 64          // (n, half-of-i): z = n*2 + half
#define UNITS  31

// ws layout: [0, 75497472) fp32 partials, 64 chunks x OUT_ELEMS.
// NO staging buffers: both fp32->bf16 conversions are folded into the GEMM.
#define PART_BYTES   75497472ull
#define PART62_BYTES 73138176ull   // fallback: 62-chunk fp32 partials

__device__ __forceinline__ uint32_t pk_bf16(float a, float b) {
    uint32_t ua = __float_as_uint(a); ua += 0x7FFFu + ((ua >> 16) & 1u);
    uint32_t ub = __float_as_uint(b); ub += 0x7FFFu + ((ub >> 16) & 1u);
    return (ua >> 16) | (ub & 0xFFFF0000u);
}

// ---- main GEMM: block tile 64o x 32c, wave = 16o x 32c (acc 72 AGPR).
//      BOTH operands converted fp32->bf16 in-kernel (no prep kernels):
//      GO 4-buf (u&3) + X 8-ring, 2 units per barrier phase (16 barriers),
//      loads issued phase-start, packed+ds_written phase-end (T14 split). ----
__global__ __launch_bounds__(256, 2) void convbw3_kernel(
    const float* __restrict__ inp,     // fp32 [n][128][64][64]
    const float* __restrict__ gout,    // fp32 [n][256][62][62]
    float* __restrict__ part)          // partials, chunk-major
{
    __shared__ __align__(16) short GO_sh[4][64 * 64];   // 4 x 8192 B
    __shared__ __align__(16) short X_ring[8][32 * 64];  // 8 x 4096 B (64KB)

    const int tid  = threadIdx.x;
    const int lane = tid & 63;
    const int wave = tid >> 6;
    const int l15  = lane & 15;
    const int quad = lane >> 4;

    // XCD swizzle (R4-proven): ids round-robin the 8 XCDs; each XCD gets
    // 128 consecutive sw -> 8 z-chunks (4 images) co-located for L2 reuse.
    const uint32_t bid = (blockIdx.z * 4 + blockIdx.y) * 4 + blockIdx.x;
    const uint32_t sw  = (bid & 7u) * 128u + (bid >> 3);   // 1024 = 8*128
    const int xs = sw & 3;
    const int ys = (sw >> 2) & 3;
    const int zs = sw >> 4;

    const int Mbase = xs * 64;         // 0..192
    const int Cbase = ys * 32;         // 0..96
    const int nimg  = zs >> 1;         // image
    const int i0    = (zs & 1) * 31;   // i in [i0, i0+31)

    // ---- GO in-kernel staging: 4 threads/row, thread covers 16 shorts ----
    const int grow = tid >> 2;         // o offset within 64-row tile
    const int gj   = (tid & 3) * 16;   // float/short offset within row
    const float* g_src = gout
        + (size_t)(nimg * 256 + Mbase + grow) * HW_GO + gj;
    const int gr7 = grow & 7;
    const int gc0 = ((tid & 3) * 2) ^ gr7;   // swizzled chunk of shorts gj..+7
    const int gc1 = gc0 ^ 1;                 // swizzled chunk gj+8..+15

    floatx2 gf[2][8];   // staged fp32 for 2 units (held across compute)
    auto load_gf = [&](int u, int s) {   // local unit u -> regs slot s
        const float* g = g_src + (size_t)(i0 + u) * 62;
#pragma unroll
        for (int k = 0; k < 7; ++k)
            gf[s][k] = *(const floatx2*)(g + 2 * k);
        gf[s][7] = (gj < 48) ? *(const floatx2*)(g + 14) : (floatx2){0.f, 0.f};
    };
    auto flush_gf = [&](int u, int s) {  // pack + ds_write into buf u&3
        uintx4 w0, w1;
        w0.x = pk_bf16(gf[s][0].x, gf[s][0].y);
        w0.y = pk_bf16(gf[s][1].x, gf[s][1].y);
        w0.z = pk_bf16(gf[s][2].x, gf[s][2].y);
        w0.w = pk_bf16(gf[s][3].x, gf[s][3].y);
        w1.x = pk_bf16(gf[s][4].x, gf[s][4].y);
        w1.y = pk_bf16(gf[s][5].x, gf[s][5].y);
        w1.z = pk_bf16(gf[s][6].x, gf[s][6].y);
        w1.w = pk_bf16(gf[s][7].x, gf[s][7].y);   // pk(0,0)=0: K-pad cols
        short* b = &GO_sh[u & 3][grow * 64];
        *(uintx4*)(b + (gc0 << 3)) = w0;
        *(uintx4*)(b + (gc1 << 3)) = w1;
    };

    // ---- X staging (R9-proven scheme, 8-slot ring) ----
    const int xrow_loc = wave * 8 + (lane >> 3);          // 0..31 (channel)
    const float* x_src = inp + ((size_t)(nimg * 128 + Cbase + xrow_loc) << 12)
                             + ((lane & 7) << 3);
    short* x_dst = &X_ring[0][0] + xrow_loc * 64
                 + (((lane & 7) ^ (lane >> 3)) << 3);

    floatx4 xf[2][2];   // staged fp32 for 2 rows (held across compute)
    auto load_xf = [&](int h, int s) {   // absolute input row h
        if (h < 64) {
            xf[s][0] = *(const floatx4*)(x_src + (h << 6));
            xf[s][1] = *(const floatx4*)(x_src + (h << 6) + 4);
        }
    };
    auto flush_xf = [&](int h, int s) {  // pack + ds_write into slot h&7
        if (h < 64) {
            uintx4 xp;
            xp.x = pk_bf16(xf[s][0].x, xf[s][0].y);
            xp.y = pk_bf16(xf[s][0].z, xf[s][0].w);
            xp.z = pk_bf16(xf[s][1].x, xf[s][1].y);
            xp.w = pk_bf16(xf[s][1].z, xf[s][1].w);
            *(uintx4*)(x_dst + ((h & 7) << 11)) = xp;   // 2048 shorts/slot
        }
    };

    floatx4 acc[2][9];
#pragma unroll
    for (int ni = 0; ni < 2; ++ni)
#pragma unroll
        for (int t = 0; t < 9; ++t)
            acc[ni][t] = (floatx4){0.f, 0.f, 0.f, 0.f};

    const int r7 = l15 & 7;
    auto compute = [&](int u) {          // local unit u (R7-proven core)
        const int i = i0 + u;
        const short* Gb = &GO_sh[u & 3][0];
        short8 a[2];
#pragma unroll
        for (int ks = 0; ks < 2; ++ks)
            a[ks] = *(const short8*)(
                Gb + ((wave * 16 + l15) << 6)
                   + ((((ks << 2) | quad) ^ r7) << 3));
#pragma unroll
        for (int kh = 0; kh < 3; ++kh) {
            const short* Xs = &X_ring[(i + kh) & 7][0];
#pragma unroll
            for (int ni = 0; ni < 2; ++ni) {
                const short* xrow = Xs + ((ni * 16 + l15) << 6);
#pragma unroll
                for (int ks = 0; ks < 2; ++ks) {
                    const int lc = ks * 4 + quad;
                    const intx4 d = *(const intx4*)(xrow + ((lc ^ r7) << 3));
                    const int d4 =
                        *(const int*)(xrow + ((((lc + 1) & 7) ^ r7) << 3));
                    const uint32_t e0 = (uint32_t)d.x, e1 = (uint32_t)d.y,
                                   e2 = (uint32_t)d.z, e3 = (uint32_t)d.w,
                                   e4 = (uint32_t)d4;
                    union { uint32_t u[4]; short8 s; } f0, f1, f2;
                    f0.u[0] = e0; f0.u[1] = e1; f0.u[2] = e2; f0.u[3] = e3;
                    // f1 dword k = e_k>>16 | e_{k+1}<<16 == v_perm_b32
                    f1.u[0] = __builtin_amdgcn_perm(e1, e0, 0x05040302u);
                    f1.u[1] = __builtin_amdgcn_perm(e2, e1, 0x05040302u);
                    f1.u[2] = __builtin_amdgcn_perm(e3, e2, 0x05040302u);
                    f1.u[3] = __builtin_amdgcn_perm(e4, e3, 0x05040302u);
                    f2.u[0] = e1; f2.u[1] = e2; f2.u[2] = e3; f2.u[3] = e4;
                    acc[ni][kh * 3 + 0] =
                        __builtin_amdgcn_mfma_f32_16x16x32_bf16(
                            a[ks], f0.s, acc[ni][kh * 3 + 0], 0, 0, 0);
                    acc[ni][kh * 3 + 1] =
                        __builtin_amdgcn_mfma_f32_16x16x32_bf16(
                            a[ks], f1.s, acc[ni][kh * 3 + 1], 0, 0, 0);
                    acc[ni][kh * 3 + 2] =
                        __builtin_amdgcn_mfma_f32_16x16x32_bf16(
                            a[ks], f2.s, acc[ni][kh * 3 + 2], 0, 0, 0);
                }
            }
        }
    };

    // prologue: GO units 0,1 and X rows i0..i0+3 staged + written
    load_gf(0, 0); load_gf(1, 1);
    load_xf(i0, 0); load_xf(i0 + 1, 1);
    flush_xf(i0, 0); flush_xf(i0 + 1, 1);
    load_xf(i0 + 2, 0); load_xf(i0 + 3, 1);
    flush_xf(i0 + 2, 0); flush_xf(i0 + 3, 1);
    flush_gf(0, 0); flush_gf(1, 1);

    // 15 phases x 2 units + 1 tail unit = 31 units, 16 barriers total
#pragma unroll 1
    for (int p = 0; p < 15; ++p) {
        const int u = 2 * p;
        __syncthreads();   // seals last phase's ds_writes for this compute

        // issue next-phase loads (complete under ~2 units of compute)
        if (u + 2 < UNITS) load_gf(u + 2, 0);
        if (u + 3 < UNITS) load_gf(u + 3, 1);
        load_xf(i0 + u + 4, 0);
        load_xf(i0 + u + 5, 1);

        compute(u);
        compute(u + 1);

        // pack + write (targets not read this phase; sealed by next barrier)
        if (u + 2 < UNITS) flush_gf(u + 2, 0);
        if (u + 3 < UNITS) flush_gf(u + 3, 1);
        flush_xf(i0 + u + 4, 0);
        flush_xf(i0 + u + 5, 1);
    }
    __syncthreads();
    compute(30);           // tail (staged by phase 14)

    // epilogue: C/D layout col=lane&15, row=quad*4+reg (m89/m91)
    float* baseo = part + (size_t)zs * OUT_ELEMS;
    const int o_base = Mbase + wave * 16 + quad * 4;
#pragma unroll
    for (int ni = 0; ni < 2; ++ni) {
        const int c = Cbase + ni * 16 + l15;
#pragma unroll
        for (int t = 0; t < 9; ++t)
#pragma unroll
            for (int r = 0; r < 4; ++r)
                baseo[(size_t)(o_base + r) * 1152 + c * 9 + t] =
                    acc[ni][t][r];
    }
}

__global__ __launch_bounds__(256) void reduce_kernel(
    const floatx4* __restrict__ ws, floatx4* __restrict__ out, int nchunk)
{
    const int idx = blockIdx.x * 256 + threadIdx.x;
    floatx4 s = {0.f, 0.f, 0.f, 0.f};
#pragma unroll 4
    for (int ch = 0; ch < nchunk; ++ch)
        s += ws[(size_t)ch * (OUT_ELEMS / 4) + idx];
    out[idx] = s;
}

// ================= fallback (fp32 direct, self-contained) =================
template<bool USE_ATOMIC>
__global__ __launch_bounds__(256, 1) void convbw_kernel(
    const float* __restrict__ inp, const float* __restrict__ gout,
    float* __restrict__ dst)
{
    __shared__ __align__(16) short GO_sh[128][72];
    __shared__ __align__(16) short X_sh[3][3][32][72];
    const int tid = threadIdx.x, lane = tid & 63, wave = tid >> 6;
    const int l15 = lane & 15, quad = lane >> 4;
    const int Mbase = blockIdx.x * 128, Cbase = blockIdx.y * 32;
    const int chunk = blockIdx.z;
    const int gl = tid & 31, grow0 = tid >> 5, xl = tid & 15, xrow0 = tid >> 4;
    floatx2 go_r[16];
    floatx4 x_r[6];
    auto issue_loads = [&](int u) {
        const int n_img = u / 62, i = u - n_img * 62;
        const float* bg = gout + (size_t)(n_img * 256 + Mbase) * HW_GO + i * 62;
        const float* bi = inp + (size_t)(n_img * 128 + Cbase) * HW_IN + i * 64;
#pragma unroll
        for (int p = 0; p < 16; ++p)
            go_r[p] = *(const floatx2*)(bg + (size_t)(grow0 + p * 8) * HW_GO + gl * 2);
#pragma unroll
        for (int p = 0; p < 6; ++p) {
            const int row = xrow0 + p * 16, c = row & 31, kh = row >> 5;
            x_r[p] = *(const floatx4*)(bi + (size_t)c * HW_IN + kh * 64 + xl * 4);
        }
    };
    auto flush = [&]() {
#pragma unroll
        for (int p = 0; p < 16; ++p) {
            uint32_t v = pk_bf16(go_r[p].x, go_r[p].y);
            if (gl == 31) v = 0;
            *(uint32_t*)&GO_sh[grow0 + p * 8][gl * 2] = v;
        }
#pragma unroll
        for (int p = 0; p < 6; ++p) {
            const int row = xrow0 + p * 16, c = row & 31, kh = row >> 5;
            uint32_t lo = pk_bf16(x_r[p].x, x_r[p].y);
            uint32_t hi = pk_bf16(x_r[p].z, x_r[p].w);
            uint32_t nlo = (uint32_t)__shfl((int)lo, (lane + 1) & 63);
            uintx2 v0 = {lo, hi};
            uintx2 v1 = {(lo >> 16) | (hi << 16), (hi >> 16) | (nlo << 16)};
            uintx2 v2 = {hi, nlo};
            *(uintx2*)&X_sh[kh][0][c][xl * 4] = v0;
            *(uintx2*)&X_sh[kh][1][c][xl * 4] = v1;
            *(uintx2*)&X_sh[kh][2][c][xl * 4] = v2;
        }
    };
    floatx4 acc[2][2][9];
#pragma unroll
    for (int mi = 0; mi < 2; ++mi)
#pragma unroll
        for (int ni = 0; ni < 2; ++ni)
#pragma unroll
            for (int t = 0; t < 9; ++t) acc[mi][ni][t] = (floatx4){0,0,0,0};
    issue_loads(chunk * 32);
#pragma unroll 1
    for (int uu = 0; uu < 32; ++uu) {
        flush();
        if (uu + 1 < 32) issue_loads(chunk * 32 + uu + 1);
        __syncthreads();
#pragma unroll
        for (int ks = 0; ks < 2; ++ks) {
            const int kc = ks * 32 + quad * 8;
            const short8 a0 = *(const short8*)&GO_sh[wave * 32 + l15][kc];
            const short8 a1 = *(const short8*)&GO_sh[wave * 32 + 16 + l15][kc];
#pragma unroll
            for (int kh = 0; kh < 3; ++kh)
#pragma unroll
                for (int kw = 0; kw < 3; ++kw) {
                    const int t = kh * 3 + kw;
#pragma unroll
                    for (int ni = 0; ni < 2; ++ni) {
                        const short8 b = *(const short8*)&X_sh[kh][kw][ni * 16 + l15][kc];
                        acc[0][ni][t] = __builtin_amdgcn_mfma_f32_16x16x32_bf16(a0, b, acc[0][ni][t], 0, 0, 0);
                        acc[1][ni][t] = __builtin_amdgcn_mfma_f32_16x16x32_bf16(a1, b, acc[1][ni][t], 0, 0, 0);
                    }
                }
        }
        __syncthreads();
    }
    float* base = USE_ATOMIC ? dst : dst + (size_t)chunk * OUT_ELEMS;
#pragma unroll
    for (int mi = 0; mi < 2; ++mi) {
        const int o_base = Mbase + wave * 32 + mi * 16 + quad * 4;
#pragma unroll
        for (int ni = 0; ni < 2; ++ni) {
            const int c = Cbase + ni * 16 + l15;
#pragma unroll
            for (int t = 0; t < 9; ++t)
#pragma unroll
                for (int r = 0; r < 4; ++r) {
                    const size_t off = (size_t)(o_base + r) * 1152 + c * 9 + t;
                    if (USE_ATOMIC) atomicAdd(base + off, acc[mi][ni][t][r]);
                    else base[off] = acc[mi][ni][t][r];
                }
        }
    }
}

extern "C" void kernel_launch(void* const* d_in, const int* in_sizes, int n_in,
                              void* d_out, int out_size, void* d_ws, size_t ws_size,
                              hipStream_t stream) {
    const float* inp  = (const float*)d_in[0];
    const float* gout = (const float*)d_in[1];

    if (ws_size >= PART_BYTES) {
        float* part = (float*)d_ws;
        convbw3_kernel<<<dim3(4, 4, NCHUNK), 256, 0, stream>>>(
            inp, gout, part);
        reduce_kernel<<<OUT_ELEMS / 4 / 256, 256, 0, stream>>>(
            (const floatx4*)part, (floatx4*)d_out, NCHUNK);
        return;
    }
    // fallback: fp32-direct path
    dim3 grid(2, 4, 62);
    if (ws_size >= PART62_BYTES) {
        float* part = (float*)d_ws;
        convbw_kernel<false><<<grid, 256, 0, stream>>>(inp, gout, part);
        reduce_kernel<<<OUT_ELEMS / 4 / 256, 256, 0, stream>>>(
            (const floatx4*)part, (floatx4*)d_out, 62);
    } else {
        hipMemsetAsync(d_out, 0, (size_t)out_size * sizeof(float), stream);
        convbw_kernel<true><<<grid, 256, 0, stream>>>(inp, gout, (float*)d_out);
    }
}